// Round 1
// baseline (325.467 us; speedup 1.0000x reference)
//
#include <hip/hip_runtime.h>
#include <hip/hip_bf16.h>
#include <stdint.h>
#include <stddef.h>

#define SEQ 4096
#define DIN 1024
#define DQK 1024
#define DV  1024

typedef __bf16 bf16;
typedef __bf16 bf16x4 __attribute__((ext_vector_type(4)));
typedef __bf16 bf16x8 __attribute__((ext_vector_type(8)));
typedef float  f32x4  __attribute__((ext_vector_type(4)));

// ---------------- K0a: elementwise split fp32 -> bf16 hi/lo ----------------
__global__ __launch_bounds__(256) void split_f32(const float* __restrict__ in,
                                                 bf16* __restrict__ hi,
                                                 bf16* __restrict__ lo, int n4) {
  int i = blockIdx.x * 256 + threadIdx.x;
  if (i >= n4) return;
  const float4 v = ((const float4*)in)[i];
  float a[4] = {v.x, v.y, v.z, v.w};
  bf16x4 h, l;
#pragma unroll
  for (int t = 0; t < 4; ++t) {
    bf16 hh = (bf16)a[t];
    h[t] = hh;
    l[t] = (bf16)(a[t] - (float)hh);
  }
  ((bf16x4*)hi)[i] = h;
  ((bf16x4*)lo)[i] = l;
}

// ---------------- K0b: W (K x N, fp32) -> W^T (N x K, bf16 hi[/lo]) ----------------
template <bool DO_SPLIT>
__global__ __launch_bounds__(256) void wtrans(const float* __restrict__ W,
                                              bf16* __restrict__ outH,
                                              bf16* __restrict__ outL) {
  __shared__ float t[32][33];
  const int bx = blockIdx.x & 31;   // n-tile
  const int by = blockIdx.x >> 5;   // k-tile
  const int tx = threadIdx.x & 31;
  const int ty = threadIdx.x >> 5;  // 0..7
#pragma unroll
  for (int r = 0; r < 32; r += 8)
    t[ty + r][tx] = W[(size_t)(by * 32 + ty + r) * DQK + bx * 32 + tx];
  __syncthreads();
#pragma unroll
  for (int r = 0; r < 32; r += 8) {
    float v = t[tx][ty + r];  // = W[by*32+tx][bx*32+ty+r]
    size_t o = (size_t)(bx * 32 + ty + r) * DIN + by * 32 + tx;
    bf16 h = (bf16)v;
    outH[o] = h;
    if (DO_SPLIT) outL[o] = (bf16)(v - (float)h);
  }
}

// ---------------- global -> LDS staging of one 128x32 bf16 tile ----------------
// LDS layout is linear [128][32]; global_load_lds writes lane*16B from a
// wave-uniform LDS base (guide §5); per-lane global source address.
__device__ __forceinline__ void stage_tile(const bf16* __restrict__ g, int ld,
                                           int row0, int k0, bf16* lds,
                                           int wid, int lane) {
#pragma unroll
  for (int c = 0; c < 2; ++c) {
    const int q = wid * 2 + c;  // chunk 0..7: rows [q*16, q*16+16)
    const bf16* src =
        g + (size_t)(row0 + q * 16 + (lane >> 2)) * ld + k0 + (lane & 3) * 8;
    __builtin_amdgcn_global_load_lds(
        (const __attribute__((address_space(1))) void*)src,
        (__attribute__((address_space(3))) void*)(lds + q * 512), 16, 0, 0);
  }
}

__device__ __forceinline__ bf16x8 ldsfrag(const bf16* s, int rbase, int lane) {
  return *(const bf16x8*)&s[(rbase + (lane & 15)) * 32 + ((lane >> 4) * 8)];
}

// ---------------- shared MFMA GEMM core (m97 pattern, 128x128 tile) ----------
// Computes out[m][n] = sum_k A[m][k] * B[n][k]  (B given in "B^T" N x K form).
// SPLIT modes use two-term bf16 decomposition: hi*hi + hi*lo + lo*hi.
enum { M_SPLITOUT = 0, M_BF16OUT = 1, M_SCORE = 2, M_PV = 3 };

template <int MODE>
__global__ __launch_bounds__(256, 2) void gemm_kernel(
    const bf16* __restrict__ Agh, const bf16* __restrict__ Agl,
    const bf16* __restrict__ Bgh, const bf16* __restrict__ Bgl,
    int lda, int ldb, int nk_in, int nbn,
    float* __restrict__ outF, bf16* __restrict__ outH, bf16* __restrict__ outL,
    int ldo) {
  constexpr bool SPLIT = (MODE == M_SPLITOUT || MODE == M_SCORE);
  __shared__ bf16 sAh[128 * 32];
  __shared__ bf16 sBh[128 * 32];
  __shared__ bf16 sAl[SPLIT ? 128 * 32 : 8];
  __shared__ bf16 sBl[SPLIT ? 128 * 32 : 8];

  int bm, bn, nk;
  if constexpr (MODE == M_SCORE) {
    // causal lower-triangle tile mapping: t -> (bi, bj), bj <= bi
    const int t = blockIdx.x;
    int bi = (int)((sqrtf(8.0f * (float)t + 1.0f) - 1.0f) * 0.5f);
    while ((bi + 1) * (bi + 2) / 2 <= t) ++bi;
    while (bi * (bi + 1) / 2 > t) --bi;
    bm = bi;
    bn = t - bi * (bi + 1) / 2;
    nk = nk_in;
  } else {
    bm = blockIdx.x / nbn;
    bn = blockIdx.x % nbn;
    nk = (MODE == M_PV) ? (bm + 1) * 4 : nk_in;  // PV: k-extent to diagonal
  }

  const int wid = threadIdx.x >> 6;
  const int lane = threadIdx.x & 63;
  const int wr = (wid >> 1) * 64;  // wave's 64x64 quadrant
  const int wc = (wid & 1) * 64;

  f32x4 acc[4][4];
#pragma unroll
  for (int i = 0; i < 4; ++i)
#pragma unroll
    for (int j = 0; j < 4; ++j) acc[i][j] = (f32x4)(0.0f);

  for (int kt = 0; kt < nk; ++kt) {
    const int k0 = kt * 32;
    __syncthreads();  // previous tile's compute done before overwrite
    stage_tile(Agh, lda, bm * 128, k0, sAh, wid, lane);
    stage_tile(Bgh, ldb, bn * 128, k0, sBh, wid, lane);
    if constexpr (SPLIT) {
      stage_tile(Agl, lda, bm * 128, k0, sAl, wid, lane);
      stage_tile(Bgl, ldb, bn * 128, k0, sBl, wid, lane);
    }
    __syncthreads();  // compiler drains vmcnt before barrier -> tile ready

    bf16x8 ah[4], bh[4];
#pragma unroll
    for (int i = 0; i < 4; ++i) ah[i] = ldsfrag(sAh, wr + i * 16, lane);
#pragma unroll
    for (int j = 0; j < 4; ++j) bh[j] = ldsfrag(sBh, wc + j * 16, lane);
#pragma unroll
    for (int i = 0; i < 4; ++i)
#pragma unroll
      for (int j = 0; j < 4; ++j)
        acc[i][j] = __builtin_amdgcn_mfma_f32_16x16x32_bf16(ah[i], bh[j],
                                                            acc[i][j], 0, 0, 0);
    if constexpr (SPLIT) {
      bf16x8 bl[4];
#pragma unroll
      for (int j = 0; j < 4; ++j) bl[j] = ldsfrag(sBl, wc + j * 16, lane);
#pragma unroll
      for (int i = 0; i < 4; ++i)
#pragma unroll
        for (int j = 0; j < 4; ++j)
          acc[i][j] = __builtin_amdgcn_mfma_f32_16x16x32_bf16(
              ah[i], bl[j], acc[i][j], 0, 0, 0);
      bf16x8 al[4];
#pragma unroll
      for (int i = 0; i < 4; ++i) al[i] = ldsfrag(sAl, wr + i * 16, lane);
#pragma unroll
      for (int i = 0; i < 4; ++i)
#pragma unroll
        for (int j = 0; j < 4; ++j)
          acc[i][j] = __builtin_amdgcn_mfma_f32_16x16x32_bf16(
              al[i], bh[j], acc[i][j], 0, 0, 0);
    }
  }

  // epilogue — C/D layout (m89-verified): col = lane&15, row = (lane>>4)*4 + r
  const int r0 = bm * 128 + wr + ((lane >> 4) * 4);
  const int c0 = bn * 128 + wc + (lane & 15);
#pragma unroll
  for (int i = 0; i < 4; ++i)
#pragma unroll
    for (int j = 0; j < 4; ++j)
#pragma unroll
      for (int r = 0; r < 4; ++r) {
        const int row = r0 + i * 16 + r;
        const int col = c0 + j * 16;
        const float v = acc[i][j][r];
        if constexpr (MODE == M_SPLITOUT) {
          bf16 h = (bf16)v;
          outH[(size_t)row * ldo + col] = h;
          outL[(size_t)row * ldo + col] = (bf16)(v - (float)h);
        } else if constexpr (MODE == M_BF16OUT) {
          outH[(size_t)row * ldo + col] = (bf16)v;
        } else {
          outF[(size_t)row * ldo + col] = v;
        }
      }
}

// ---------------- row softmax: S (fp32) -> P (bf16), scale 1/32, causal ------
__global__ __launch_bounds__(256) void softmax_rows(const float* __restrict__ S,
                                                    bf16* __restrict__ P) {
  const int wid = threadIdx.x >> 6;
  const int lane = threadIdx.x & 63;
  const int row = blockIdx.x * 4 + wid;
  const int len = row + 1;                   // causal extent
  const int ext = ((row >> 7) + 1) << 7;     // zero-fill to 128-tile boundary
  const float* s = S + (size_t)row * SEQ;
  bf16* p = P + (size_t)row * SEQ;

  float m = -1e30f;
  for (int j = lane; j < len; j += 64) m = fmaxf(m, s[j]);
#pragma unroll
  for (int off = 32; off > 0; off >>= 1) m = fmaxf(m, __shfl_xor(m, off));
  m *= 0.03125f;  // max(s)/32 == max(s/32)

  float l = 0.f;
  for (int j = lane; j < len; j += 64) l += __expf(s[j] * 0.03125f - m);
#pragma unroll
  for (int off = 32; off > 0; off >>= 1) l += __shfl_xor(l, off);
  const float inv = 1.0f / l;

  for (int j = lane; j < ext; j += 64) {
    float v = (j < len) ? __expf(s[j] * 0.03125f - m) * inv : 0.0f;
    p[j] = (bf16)v;
  }
}

// ---------------- launch ----------------
extern "C" void kernel_launch(void* const* d_in, const int* in_sizes, int n_in,
                              void* d_out, int out_size, void* d_ws,
                              size_t ws_size, hipStream_t stream) {
  const float* x = (const float*)d_in[0];
  const float* Wq = (const float*)d_in[1];
  const float* Wk = (const float*)d_in[2];
  const float* Wv = (const float*)d_in[3];
  float* out = (float*)d_out;
  char* ws = (char*)d_ws;

  const size_t MB = 1024 * 1024;
  // live ranges: [QH..KL 0-32M] dead after scores -> P aliases it.
  //              [XH/XL/W* 40-66M] dead after projections -> S (40-104M) overlays.
  const size_t OFF_QH = 0, OFF_QL = 8 * MB, OFF_KH = 16 * MB, OFF_KL = 24 * MB;
  const size_t OFF_P = 0;
  const size_t OFF_VT = 32 * MB;
  const size_t OFF_S = 40 * MB;
  const size_t OFF_XH = 40 * MB, OFF_XL = 48 * MB;
  const size_t OFF_WQH = 56 * MB, OFF_WQL = 58 * MB;
  const size_t OFF_WKH = 60 * MB, OFF_WKL = 62 * MB, OFF_WVT = 64 * MB;
  const size_t NEEDED = 104 * MB;
  if (ws_size < NEEDED) return;  // loud failure: harness will flag mismatch

  bf16* qh = (bf16*)(ws + OFF_QH);
  bf16* ql = (bf16*)(ws + OFF_QL);
  bf16* kh = (bf16*)(ws + OFF_KH);
  bf16* kl = (bf16*)(ws + OFF_KL);
  bf16* pp = (bf16*)(ws + OFF_P);
  bf16* vt = (bf16*)(ws + OFF_VT);
  float* S = (float*)(ws + OFF_S);
  bf16* xh = (bf16*)(ws + OFF_XH);
  bf16* xl = (bf16*)(ws + OFF_XL);
  bf16* wqh = (bf16*)(ws + OFF_WQH);
  bf16* wql = (bf16*)(ws + OFF_WQL);
  bf16* wkh = (bf16*)(ws + OFF_WKH);
  bf16* wkl = (bf16*)(ws + OFF_WKL);
  bf16* wvt = (bf16*)(ws + OFF_WVT);

  // K0: conversions
  split_f32<<<(SEQ * DIN / 4 + 255) / 256, 256, 0, stream>>>(x, xh, xl,
                                                             SEQ * DIN / 4);
  wtrans<true><<<1024, 256, 0, stream>>>(Wq, wqh, wql);
  wtrans<true><<<1024, 256, 0, stream>>>(Wk, wkh, wkl);
  wtrans<false><<<1024, 256, 0, stream>>>(Wv, wvt, nullptr);

  // K1: Q, K projections (split precision), V^T projection (plain bf16)
  gemm_kernel<M_SPLITOUT><<<(SEQ / 128) * (DQK / 128), 256, 0, stream>>>(
      xh, xl, wqh, wql, DIN, DIN, DIN / 32, DQK / 128, nullptr, qh, ql, DQK);
  gemm_kernel<M_SPLITOUT><<<(SEQ / 128) * (DQK / 128), 256, 0, stream>>>(
      xh, xl, wkh, wkl, DIN, DIN, DIN / 32, DQK / 128, nullptr, kh, kl, DQK);
  // V^T[n][m] = sum_k WvT[n][k] * x[m][k]  -> coalesced native store of V^T
  gemm_kernel<M_BF16OUT><<<(DV / 128) * (SEQ / 128), 256, 0, stream>>>(
      wvt, nullptr, xh, nullptr, DIN, DIN, DIN / 32, SEQ / 128, nullptr, vt,
      nullptr, SEQ);

  // K2: causal score tiles S = Q K^T (split precision), fp32 out
  gemm_kernel<M_SCORE><<<(SEQ / 128) * (SEQ / 128 + 1) / 2, 256, 0, stream>>>(
      qh, ql, kh, kl, DQK, DQK, DQK / 32, 0, S, nullptr, nullptr, SEQ);

  // K3: row softmax -> P bf16 (zero-filled to tile boundary)
  softmax_rows<<<SEQ / 4, 256, 0, stream>>>(S, pp);

  // K4: O = P V  (A = P [T x T], B = V^T in N x K form), fp32 out
  gemm_kernel<M_PV><<<(SEQ / 128) * (DV / 128), 256, 0, stream>>>(
      pp, nullptr, vt, nullptr, SEQ, SEQ, 0, DV / 128, out, nullptr, nullptr,
      DV);
}

// Round 2
// 291.220 us; speedup vs baseline: 1.1176x; 1.1176x over previous
//
#include <hip/hip_runtime.h>
#include <hip/hip_bf16.h>
#include <stdint.h>
#include <stddef.h>

#define SEQ 4096
#define DIN 1024
#define DQK 1024
#define DV  1024

typedef __bf16 bf16;
typedef __bf16 bf16x4 __attribute__((ext_vector_type(4)));
typedef __bf16 bf16x8 __attribute__((ext_vector_type(8)));
typedef float  f32x4  __attribute__((ext_vector_type(4)));

// ---------------- K0a: elementwise split fp32 -> bf16 hi/lo ----------------
__global__ __launch_bounds__(256) void split_f32(const float* __restrict__ in,
                                                 bf16* __restrict__ hi,
                                                 bf16* __restrict__ lo, int n4) {
  int i = blockIdx.x * 256 + threadIdx.x;
  if (i >= n4) return;
  const float4 v = ((const float4*)in)[i];
  float a[4] = {v.x, v.y, v.z, v.w};
  bf16x4 h, l;
#pragma unroll
  for (int t = 0; t < 4; ++t) {
    bf16 hh = (bf16)a[t];
    h[t] = hh;
    l[t] = (bf16)(a[t] - (float)hh);
  }
  ((bf16x4*)hi)[i] = h;
  ((bf16x4*)lo)[i] = l;
}

// ---------------- K0b: W (K x N, fp32) -> W^T (N x K, bf16 hi[/lo]) ----------------
template <bool DO_SPLIT>
__global__ __launch_bounds__(256) void wtrans(const float* __restrict__ W,
                                              bf16* __restrict__ outH,
                                              bf16* __restrict__ outL) {
  __shared__ float t[32][33];
  const int bx = blockIdx.x & 31;   // n-tile
  const int by = blockIdx.x >> 5;   // k-tile
  const int tx = threadIdx.x & 31;
  const int ty = threadIdx.x >> 5;  // 0..7
#pragma unroll
  for (int r = 0; r < 32; r += 8)
    t[ty + r][tx] = W[(size_t)(by * 32 + ty + r) * DQK + bx * 32 + tx];
  __syncthreads();
#pragma unroll
  for (int r = 0; r < 32; r += 8) {
    float v = t[tx][ty + r];  // = W[by*32+tx][bx*32+ty+r]
    size_t o = (size_t)(bx * 32 + ty + r) * DIN + by * 32 + tx;
    bf16 h = (bf16)v;
    outH[o] = h;
    if (DO_SPLIT) outL[o] = (bf16)(v - (float)h);
  }
}

// ---------------- global -> LDS staging of one 128x32 bf16 tile ----------------
__device__ __forceinline__ void stage_tile(const bf16* __restrict__ g, int ld,
                                           int row0, int k0, bf16* lds,
                                           int wid, int lane) {
#pragma unroll
  for (int c = 0; c < 2; ++c) {
    const int q = wid * 2 + c;  // chunk 0..7: rows [q*16, q*16+16)
    const bf16* src =
        g + (size_t)(row0 + q * 16 + (lane >> 2)) * ld + k0 + (lane & 3) * 8;
    __builtin_amdgcn_global_load_lds(
        (const __attribute__((address_space(1))) void*)src,
        (__attribute__((address_space(3))) void*)(lds + q * 512), 16, 0, 0);
  }
}

__device__ __forceinline__ bf16x8 ldsfrag(const bf16* s, int rbase, int lane) {
  return *(const bf16x8*)&s[(rbase + (lane & 15)) * 32 + ((lane >> 4) * 8)];
}

// ---------------- shared MFMA GEMM core (m97 pattern, 128x128 tile) ----------
// Computes out[m][n] = sum_k A[m][k] * B[n][k]  (B given in "B^T" N x K form).
// SPLIT modes use two-term bf16 decomposition: hi*hi + hi*lo + lo*hi.
// M_PV is split-K over causal extent: slice c covers K-steps [c*32, c*32+32);
// slice 0 writes `outF` directly, slices 1..3 write fp32 partials in outP.
enum { M_SPLITOUT = 0, M_BF16OUT = 1, M_SCORE = 2, M_PV = 3 };

template <int MODE>
__global__ __launch_bounds__(256, 2) void gemm_kernel(
    const bf16* __restrict__ Agh, const bf16* __restrict__ Agl,
    const bf16* __restrict__ Bgh, const bf16* __restrict__ Bgl,
    int lda, int ldb, int nk_in, int nbn,
    float* __restrict__ outF, bf16* __restrict__ outH, bf16* __restrict__ outL,
    float* __restrict__ outP, int ldo) {
  constexpr bool SPLIT = (MODE == M_SPLITOUT || MODE == M_SCORE);
  __shared__ bf16 sAh[128 * 32];
  __shared__ bf16 sBh[128 * 32];
  __shared__ bf16 sAl[SPLIT ? 128 * 32 : 8];
  __shared__ bf16 sBl[SPLIT ? 128 * 32 : 8];

  int bm, bn, nk, ks0 = 0, slice = 0;
  if constexpr (MODE == M_SCORE) {
    // causal lower-triangle tile mapping: t -> (bi, bj), bj <= bi
    const int t = blockIdx.x;
    int bi = (int)((sqrtf(8.0f * (float)t + 1.0f) - 1.0f) * 0.5f);
    while ((bi + 1) * (bi + 2) / 2 <= t) ++bi;
    while (bi * (bi + 1) / 2 > t) --bi;
    bm = bi;
    bn = t - bi * (bi + 1) / 2;
    nk = nk_in;
  } else if constexpr (MODE == M_PV) {
    // balanced split-K over the causal extent. 640 blocks:
    // group g=blk>>3 in [0,80) -> (bm, slice); bn = blk&7.
    const int g = blockIdx.x >> 3;
    bn = blockIdx.x & 7;
    if (g < 8) {
      bm = g;
      slice = 0;
    } else if (g < 24) {
      const int i = g - 8;
      bm = 8 + (i >> 1);
      slice = i & 1;
    } else if (g < 48) {
      const int i = g - 24;
      bm = 16 + i / 3;
      slice = i % 3;
    } else {
      const int i = g - 48;
      bm = 24 + (i >> 2);
      slice = i & 3;
    }
    ks0 = slice * 32;
    const int kend = (bm + 1) * 4;  // causal K-step extent for this row-block
    nk = (ks0 + 32 < kend) ? ks0 + 32 : kend;
  } else {
    bm = blockIdx.x / nbn;
    bn = blockIdx.x % nbn;
    nk = nk_in;
  }

  const int wid = threadIdx.x >> 6;
  const int lane = threadIdx.x & 63;
  const int wr = (wid >> 1) * 64;  // wave's 64x64 quadrant
  const int wc = (wid & 1) * 64;

  f32x4 acc[4][4];
#pragma unroll
  for (int i = 0; i < 4; ++i)
#pragma unroll
    for (int j = 0; j < 4; ++j) acc[i][j] = (f32x4)(0.0f);

  for (int kt = ks0; kt < nk; ++kt) {
    const int k0 = kt * 32;
    __syncthreads();  // previous tile's compute done before overwrite
    stage_tile(Agh, lda, bm * 128, k0, sAh, wid, lane);
    stage_tile(Bgh, ldb, bn * 128, k0, sBh, wid, lane);
    if constexpr (SPLIT) {
      stage_tile(Agl, lda, bm * 128, k0, sAl, wid, lane);
      stage_tile(Bgl, ldb, bn * 128, k0, sBl, wid, lane);
    }
    __syncthreads();  // compiler drains vmcnt before barrier -> tile ready

    bf16x8 ah[4], bh[4];
#pragma unroll
    for (int i = 0; i < 4; ++i) ah[i] = ldsfrag(sAh, wr + i * 16, lane);
#pragma unroll
    for (int j = 0; j < 4; ++j) bh[j] = ldsfrag(sBh, wc + j * 16, lane);
#pragma unroll
    for (int i = 0; i < 4; ++i)
#pragma unroll
      for (int j = 0; j < 4; ++j)
        acc[i][j] = __builtin_amdgcn_mfma_f32_16x16x32_bf16(ah[i], bh[j],
                                                            acc[i][j], 0, 0, 0);
    if constexpr (SPLIT) {
      bf16x8 bl[4];
#pragma unroll
      for (int j = 0; j < 4; ++j) bl[j] = ldsfrag(sBl, wc + j * 16, lane);
#pragma unroll
      for (int i = 0; i < 4; ++i)
#pragma unroll
        for (int j = 0; j < 4; ++j)
          acc[i][j] = __builtin_amdgcn_mfma_f32_16x16x32_bf16(
              ah[i], bl[j], acc[i][j], 0, 0, 0);
      bf16x8 al[4];
#pragma unroll
      for (int i = 0; i < 4; ++i) al[i] = ldsfrag(sAl, wr + i * 16, lane);
#pragma unroll
      for (int i = 0; i < 4; ++i)
#pragma unroll
        for (int j = 0; j < 4; ++j)
          acc[i][j] = __builtin_amdgcn_mfma_f32_16x16x32_bf16(
              al[i], bh[j], acc[i][j], 0, 0, 0);
    }
  }

  // epilogue — C/D layout (m89-verified): col = lane&15, row = (lane>>4)*4 + r
  const int r0 = bm * 128 + wr + ((lane >> 4) * 4);
  const int c0 = bn * 128 + wc + (lane & 15);
  float* dstF = outF;
  if constexpr (MODE == M_PV) {
    if (slice > 0) dstF = outP + (size_t)(slice - 1) * SEQ * DV;
  }
#pragma unroll
  for (int i = 0; i < 4; ++i)
#pragma unroll
    for (int j = 0; j < 4; ++j)
#pragma unroll
      for (int r = 0; r < 4; ++r) {
        const int row = r0 + i * 16 + r;
        const int col = c0 + j * 16;
        const float v = acc[i][j][r];
        if constexpr (MODE == M_SPLITOUT) {
          bf16 h = (bf16)v;
          outH[(size_t)row * ldo + col] = h;
          outL[(size_t)row * ldo + col] = (bf16)(v - (float)h);
        } else if constexpr (MODE == M_BF16OUT) {
          outH[(size_t)row * ldo + col] = (bf16)v;
        } else {
          dstF[(size_t)row * ldo + col] = v;
        }
      }
}

// ---------------- PV split-K reduction: out += valid partial slices ----------
// slice s (partial index) is valid for rows >= 1024*(s+1).
__global__ __launch_bounds__(256) void pv_reduce(const float* __restrict__ part,
                                                 float* __restrict__ out) {
  const int idx = blockIdx.x * 256 + threadIdx.x;  // (4096-1024)*1024/4 items
  const int r = 1024 + (idx >> 8);
  const int c4 = idx & 255;
  const size_t o = (size_t)r * DV + c4 * 4;
  const size_t SL = (size_t)SEQ * DV;
  float4 acc = *(float4*)&out[o];
  const int nsl = (r >= 3072) ? 3 : (r >= 2048) ? 2 : 1;
  for (int s = 0; s < nsl; ++s) {
    const float4 p = *(const float4*)&part[s * SL + o];
    acc.x += p.x;
    acc.y += p.y;
    acc.z += p.z;
    acc.w += p.w;
  }
  *(float4*)&out[o] = acc;
}

// ---------------- row softmax: S (fp32) -> P (bf16), scale 1/32, causal ------
__global__ __launch_bounds__(256) void softmax_rows(const float* __restrict__ S,
                                                    bf16* __restrict__ P) {
  const int wid = threadIdx.x >> 6;
  const int lane = threadIdx.x & 63;
  const int row = blockIdx.x * 4 + wid;
  const int len = row + 1;                   // causal extent
  const int ext = ((row >> 7) + 1) << 7;     // zero-fill to 128-tile boundary
  const float* s = S + (size_t)row * SEQ;
  bf16* p = P + (size_t)row * SEQ;

  float m = -1e30f;
  for (int j = lane; j < len; j += 64) m = fmaxf(m, s[j]);
#pragma unroll
  for (int off = 32; off > 0; off >>= 1) m = fmaxf(m, __shfl_xor(m, off));
  m *= 0.03125f;  // max(s)/32 == max(s/32)

  float l = 0.f;
  for (int j = lane; j < len; j += 64) l += __expf(s[j] * 0.03125f - m);
#pragma unroll
  for (int off = 32; off > 0; off >>= 1) l += __shfl_xor(l, off);
  const float inv = 1.0f / l;

  for (int j = lane; j < ext; j += 64) {
    float v = (j < len) ? __expf(s[j] * 0.03125f - m) * inv : 0.0f;
    p[j] = (bf16)v;
  }
}

// ---------------- launch ----------------
extern "C" void kernel_launch(void* const* d_in, const int* in_sizes, int n_in,
                              void* d_out, int out_size, void* d_ws,
                              size_t ws_size, hipStream_t stream) {
  const float* x = (const float*)d_in[0];
  const float* Wq = (const float*)d_in[1];
  const float* Wk = (const float*)d_in[2];
  const float* Wv = (const float*)d_in[3];
  float* out = (float*)d_out;
  char* ws = (char*)d_ws;

  const size_t MB = 1024 * 1024;
  // live ranges: [QH..KL 0-32M] dead after scores -> P aliases it.
  //              [XH/XL/W* 40-66M] dead after projections -> S (40-104M) overlays.
  //              S dead after softmax -> PV partials (40-88M) overlay.
  const size_t OFF_QH = 0, OFF_QL = 8 * MB, OFF_KH = 16 * MB, OFF_KL = 24 * MB;
  const size_t OFF_P = 0;
  const size_t OFF_VT = 32 * MB;
  const size_t OFF_S = 40 * MB;
  const size_t OFF_PART = 40 * MB;  // 3 x 16MB fp32 partials (aliases dead S)
  const size_t OFF_XH = 40 * MB, OFF_XL = 48 * MB;
  const size_t OFF_WQH = 56 * MB, OFF_WQL = 58 * MB;
  const size_t OFF_WKH = 60 * MB, OFF_WKL = 62 * MB, OFF_WVT = 64 * MB;
  const size_t NEEDED = 104 * MB;
  if (ws_size < NEEDED) return;  // loud failure: harness will flag mismatch

  bf16* qh = (bf16*)(ws + OFF_QH);
  bf16* ql = (bf16*)(ws + OFF_QL);
  bf16* kh = (bf16*)(ws + OFF_KH);
  bf16* kl = (bf16*)(ws + OFF_KL);
  bf16* pp = (bf16*)(ws + OFF_P);
  bf16* vt = (bf16*)(ws + OFF_VT);
  float* S = (float*)(ws + OFF_S);
  float* part = (float*)(ws + OFF_PART);
  bf16* xh = (bf16*)(ws + OFF_XH);
  bf16* xl = (bf16*)(ws + OFF_XL);
  bf16* wqh = (bf16*)(ws + OFF_WQH);
  bf16* wql = (bf16*)(ws + OFF_WQL);
  bf16* wkh = (bf16*)(ws + OFF_WKH);
  bf16* wkl = (bf16*)(ws + OFF_WKL);
  bf16* wvt = (bf16*)(ws + OFF_WVT);

  // K0: conversions
  split_f32<<<(SEQ * DIN / 4 + 255) / 256, 256, 0, stream>>>(x, xh, xl,
                                                             SEQ * DIN / 4);
  wtrans<true><<<1024, 256, 0, stream>>>(Wq, wqh, wql);
  wtrans<true><<<1024, 256, 0, stream>>>(Wk, wkh, wkl);
  wtrans<false><<<1024, 256, 0, stream>>>(Wv, wvt, nullptr);

  // K1: Q, K projections (split precision), V^T projection (plain bf16)
  gemm_kernel<M_SPLITOUT><<<(SEQ / 128) * (DQK / 128), 256, 0, stream>>>(
      xh, xl, wqh, wql, DIN, DIN, DIN / 32, DQK / 128, nullptr, qh, ql, nullptr,
      DQK);
  gemm_kernel<M_SPLITOUT><<<(SEQ / 128) * (DQK / 128), 256, 0, stream>>>(
      xh, xl, wkh, wkl, DIN, DIN, DIN / 32, DQK / 128, nullptr, kh, kl, nullptr,
      DQK);
  // V^T[n][m] = sum_k WvT[n][k] * x[m][k]  -> coalesced native store of V^T
  gemm_kernel<M_BF16OUT><<<(DV / 128) * (SEQ / 128), 256, 0, stream>>>(
      wvt, nullptr, xh, nullptr, DIN, DIN, DIN / 32, SEQ / 128, nullptr, vt,
      nullptr, nullptr, SEQ);

  // K2: causal score tiles S = Q K^T (split precision), fp32 out
  gemm_kernel<M_SCORE><<<(SEQ / 128) * (SEQ / 128 + 1) / 2, 256, 0, stream>>>(
      qh, ql, kh, kl, DQK, DQK, DQK / 32, 0, S, nullptr, nullptr, nullptr, SEQ);

  // K3: row softmax -> P bf16 (zero-filled to tile boundary)
  softmax_rows<<<SEQ / 4, 256, 0, stream>>>(S, pp);

  // K4: O = P V, split-K balanced (640 blocks); slice 0 -> out, rest -> part
  gemm_kernel<M_PV><<<640, 256, 0, stream>>>(pp, nullptr, vt, nullptr, SEQ, SEQ,
                                             0, DV / 128, out, nullptr, nullptr,
                                             part, DV);

  // K5: add partial slices into out (rows >= 1024)
  pv_reduce<<<(SEQ - 1024) * DV / 4 / 256, 256, 0, stream>>>(part, out);
}

// Round 3
// 189.621 us; speedup vs baseline: 1.7164x; 1.5358x over previous
//
#include <hip/hip_runtime.h>
#include <hip/hip_bf16.h>
#include <stdint.h>
#include <stddef.h>

#define SEQ 4096
#define DIN 1024
#define DQK 1024
#define DV  1024

typedef __bf16 bf16;
typedef __bf16 bf16x4 __attribute__((ext_vector_type(4)));
typedef __bf16 bf16x8 __attribute__((ext_vector_type(8)));
typedef float  f32x4  __attribute__((ext_vector_type(4)));

// ---------------- K0a: elementwise split fp32 -> bf16 hi/lo ----------------
__global__ __launch_bounds__(256) void split_f32(const float* __restrict__ in,
                                                 bf16* __restrict__ hi,
                                                 bf16* __restrict__ lo, int n4) {
  int i = blockIdx.x * 256 + threadIdx.x;
  if (i >= n4) return;
  const float4 v = ((const float4*)in)[i];
  float a[4] = {v.x, v.y, v.z, v.w};
  bf16x4 h, l;
#pragma unroll
  for (int t = 0; t < 4; ++t) {
    bf16 hh = (bf16)a[t];
    h[t] = hh;
    l[t] = (bf16)(a[t] - (float)hh);
  }
  ((bf16x4*)hi)[i] = h;
  ((bf16x4*)lo)[i] = l;
}

// ---------------- K0b: W (K x N, fp32) -> W^T (N x K, bf16 hi[/lo]) --------
template <bool DO_SPLIT>
__global__ __launch_bounds__(256) void wtrans(const float* __restrict__ W,
                                              bf16* __restrict__ outH,
                                              bf16* __restrict__ outL) {
  __shared__ float t[32][33];
  const int bx = blockIdx.x & 31;   // n-tile
  const int by = blockIdx.x >> 5;   // k-tile
  const int tx = threadIdx.x & 31;
  const int ty = threadIdx.x >> 5;  // 0..7
#pragma unroll
  for (int r = 0; r < 32; r += 8)
    t[ty + r][tx] = W[(size_t)(by * 32 + ty + r) * DQK + bx * 32 + tx];
  __syncthreads();
#pragma unroll
  for (int r = 0; r < 32; r += 8) {
    float v = t[tx][ty + r];  // = W[by*32+tx][bx*32+ty+r]
    size_t o = (size_t)(bx * 32 + ty + r) * DIN + by * 32 + tx;
    bf16 h = (bf16)v;
    outH[o] = h;
    if (DO_SPLIT) outL[o] = (bf16)(v - (float)h);
  }
}

// ---------------- global -> LDS staging of one 128x32 bf16 tile -------------
__device__ __forceinline__ void stage_tile(const bf16* __restrict__ g, int ld,
                                           int row0, int k0, bf16* lds,
                                           int wid, int lane) {
#pragma unroll
  for (int c = 0; c < 2; ++c) {
    const int q = wid * 2 + c;  // chunk 0..7: rows [q*16, q*16+16)
    const bf16* src =
        g + (size_t)(row0 + q * 16 + (lane >> 2)) * ld + k0 + (lane & 3) * 8;
    __builtin_amdgcn_global_load_lds(
        (const __attribute__((address_space(1))) void*)src,
        (__attribute__((address_space(3))) void*)(lds + q * 512), 16, 0, 0);
  }
}

__device__ __forceinline__ bf16x8 ldsfrag(const bf16* s, int rbase, int lane) {
  return *(const bf16x8*)&s[(rbase + (lane & 15)) * 32 + ((lane >> 4) * 8)];
}

// ---------------- projection GEMM body (m97 pattern, 128x128 tile) ----------
// out[m][n] = sum_k A[m][k]*B[n][k]; SPLIT: two-term bf16, hi*hi+hi*lo+lo*hi,
// epilogue re-splits fp32 acc into bf16 hi+lo. Non-split: bf16 hi out only.
template <bool SPLIT>
__device__ __forceinline__ void proj_body(
    const bf16* __restrict__ Agh, const bf16* __restrict__ Agl,
    const bf16* __restrict__ Bgh, const bf16* __restrict__ Bgl,
    bf16* __restrict__ outH, bf16* __restrict__ outL, int bm, int bn, int ldo,
    bf16* sAh, bf16* sBh, bf16* sAl, bf16* sBl) {
  const int wid = threadIdx.x >> 6;
  const int lane = threadIdx.x & 63;
  const int wr = (wid >> 1) * 64;
  const int wc = (wid & 1) * 64;

  f32x4 acc[4][4];
#pragma unroll
  for (int i = 0; i < 4; ++i)
#pragma unroll
    for (int j = 0; j < 4; ++j) acc[i][j] = (f32x4)(0.0f);

  for (int kt = 0; kt < DIN / 32; ++kt) {
    const int k0 = kt * 32;
    __syncthreads();
    stage_tile(Agh, DIN, bm * 128, k0, sAh, wid, lane);
    stage_tile(Bgh, DIN, bn * 128, k0, sBh, wid, lane);
    if (SPLIT) {
      stage_tile(Agl, DIN, bm * 128, k0, sAl, wid, lane);
      stage_tile(Bgl, DIN, bn * 128, k0, sBl, wid, lane);
    }
    __syncthreads();

    bf16x8 ah[4], bh[4];
#pragma unroll
    for (int i = 0; i < 4; ++i) ah[i] = ldsfrag(sAh, wr + i * 16, lane);
#pragma unroll
    for (int j = 0; j < 4; ++j) bh[j] = ldsfrag(sBh, wc + j * 16, lane);
#pragma unroll
    for (int i = 0; i < 4; ++i)
#pragma unroll
      for (int j = 0; j < 4; ++j)
        acc[i][j] = __builtin_amdgcn_mfma_f32_16x16x32_bf16(ah[i], bh[j],
                                                            acc[i][j], 0, 0, 0);
    if (SPLIT) {
      bf16x8 bl[4];
#pragma unroll
      for (int j = 0; j < 4; ++j) bl[j] = ldsfrag(sBl, wc + j * 16, lane);
#pragma unroll
      for (int i = 0; i < 4; ++i)
#pragma unroll
        for (int j = 0; j < 4; ++j)
          acc[i][j] = __builtin_amdgcn_mfma_f32_16x16x32_bf16(
              ah[i], bl[j], acc[i][j], 0, 0, 0);
      bf16x8 al[4];
#pragma unroll
      for (int i = 0; i < 4; ++i) al[i] = ldsfrag(sAl, wr + i * 16, lane);
#pragma unroll
      for (int i = 0; i < 4; ++i)
#pragma unroll
        for (int j = 0; j < 4; ++j)
          acc[i][j] = __builtin_amdgcn_mfma_f32_16x16x32_bf16(
              al[i], bh[j], acc[i][j], 0, 0, 0);
    }
  }

  const int r0 = bm * 128 + wr + ((lane >> 4) * 4);
  const int c0 = bn * 128 + wc + (lane & 15);
#pragma unroll
  for (int i = 0; i < 4; ++i)
#pragma unroll
    for (int j = 0; j < 4; ++j)
#pragma unroll
      for (int r = 0; r < 4; ++r) {
        const size_t o = (size_t)(r0 + i * 16 + r) * ldo + (c0 + j * 16);
        const float v = acc[i][j][r];
        bf16 h = (bf16)v;
        outH[o] = h;
        if (SPLIT) outL[o] = (bf16)(v - (float)h);
      }
}

// ---------------- K1: fused Q/K (split) + V^T (plain) projections -----------
__global__ __launch_bounds__(256, 2) void fused_proj(
    const bf16* __restrict__ xh, const bf16* __restrict__ xl,
    const bf16* __restrict__ wqh, const bf16* __restrict__ wql,
    const bf16* __restrict__ wkh, const bf16* __restrict__ wkl,
    const bf16* __restrict__ wvt, bf16* __restrict__ qh, bf16* __restrict__ ql,
    bf16* __restrict__ kh, bf16* __restrict__ kl, bf16* __restrict__ vt) {
  __shared__ bf16 sAh[128 * 32];
  __shared__ bf16 sBh[128 * 32];
  __shared__ bf16 sAl[128 * 32];
  __shared__ bf16 sBl[128 * 32];
  const int b = blockIdx.x;
  if (b < 256) {
    proj_body<true>(xh, xl, wqh, wql, qh, ql, b >> 3, b & 7, DQK, sAh, sBh, sAl,
                    sBl);
  } else if (b < 512) {
    const int bb = b - 256;
    proj_body<true>(xh, xl, wkh, wkl, kh, kl, bb >> 3, bb & 7, DQK, sAh, sBh,
                    sAl, sBl);
  } else {
    const int bb = b - 512;
    // V^T[dv][seq] = sum_k WvT[dv][k] * x[seq][k]
    proj_body<false>(wvt, nullptr, xh, nullptr, vt, nullptr, bb >> 5, bb & 31,
                     SEQ, sAh, sBh, sAl, sBl);
  }
}

// ---------------- K2: causal score tiles, SINGLE bf16 pass, fp32 out --------
__global__ __launch_bounds__(256, 2) void score1(const bf16* __restrict__ qh,
                                                 const bf16* __restrict__ kh,
                                                 float* __restrict__ S) {
  __shared__ bf16 sA[128 * 32];
  __shared__ bf16 sB[128 * 32];
  // lower-triangle tile map
  const int t = blockIdx.x;
  int bi = (int)((sqrtf(8.0f * (float)t + 1.0f) - 1.0f) * 0.5f);
  while ((bi + 1) * (bi + 2) / 2 <= t) ++bi;
  while (bi * (bi + 1) / 2 > t) --bi;
  const int bm = bi;
  const int bn = t - bi * (bi + 1) / 2;

  const int wid = threadIdx.x >> 6;
  const int lane = threadIdx.x & 63;
  const int wr = (wid >> 1) * 64;
  const int wc = (wid & 1) * 64;

  f32x4 acc[4][4];
#pragma unroll
  for (int i = 0; i < 4; ++i)
#pragma unroll
    for (int j = 0; j < 4; ++j) acc[i][j] = (f32x4)(0.0f);

  for (int kt = 0; kt < DQK / 32; ++kt) {
    const int k0 = kt * 32;
    __syncthreads();
    stage_tile(qh, DQK, bm * 128, k0, sA, wid, lane);
    stage_tile(kh, DQK, bn * 128, k0, sB, wid, lane);
    __syncthreads();
    bf16x8 a[4], b[4];
#pragma unroll
    for (int i = 0; i < 4; ++i) a[i] = ldsfrag(sA, wr + i * 16, lane);
#pragma unroll
    for (int j = 0; j < 4; ++j) b[j] = ldsfrag(sB, wc + j * 16, lane);
#pragma unroll
    for (int i = 0; i < 4; ++i)
#pragma unroll
      for (int j = 0; j < 4; ++j)
        acc[i][j] = __builtin_amdgcn_mfma_f32_16x16x32_bf16(a[i], b[j],
                                                            acc[i][j], 0, 0, 0);
  }

  const int r0 = bm * 128 + wr + ((lane >> 4) * 4);
  const int c0 = bn * 128 + wc + (lane & 15);
#pragma unroll
  for (int i = 0; i < 4; ++i)
#pragma unroll
    for (int j = 0; j < 4; ++j)
#pragma unroll
      for (int r = 0; r < 4; ++r)
        S[(size_t)(r0 + i * 16 + r) * SEQ + (c0 + j * 16)] = acc[i][j][r];
}

// ---------------- K3: softmax + exact fixup of near-max entries -------------
// One wave per row. Stages the fp32 row in LDS; recomputes (exact fp32 dot of
// qh+ql, kh+kl) every entry within BAND of the approx max -> corrected max is
// the TRUE max. Writes P bf16 IN-PLACE into S (row slot r*4096 floats, first
// half), zero-filled to the 128-tile boundary. PV reads P with ld=8192.
__global__ __launch_bounds__(256) void softmax_fixup(
    float* __restrict__ S, const bf16* __restrict__ qh,
    const bf16* __restrict__ ql, const bf16* __restrict__ kh,
    const bf16* __restrict__ kl) {
  __shared__ __align__(16) float rb[4][4096];
  const int wid = threadIdx.x >> 6;
  const int lane = threadIdx.x & 63;
  const int row = blockIdx.x * 4 + wid;
  const int len = row + 1;
  const int ext = ((row >> 7) + 1) << 7;
  float* srow = S + (size_t)row * SEQ;
  float* rbw = rb[wid];

  // pass A: stage row, approx max
  float m0 = -3.0e38f;
  for (int j = lane * 4; j < len; j += 256) {
    float4 v = *(const float4*)(srow + j);
    *(float4*)&rbw[j] = v;
    if (j + 0 < len) m0 = fmaxf(m0, v.x);
    if (j + 1 < len) m0 = fmaxf(m0, v.y);
    if (j + 2 < len) m0 = fmaxf(m0, v.z);
    if (j + 3 < len) m0 = fmaxf(m0, v.w);
  }
#pragma unroll
  for (int o = 32; o > 0; o >>= 1) m0 = fmaxf(m0, __shfl_xor(m0, o));
  __syncthreads();

  // preload q_row (fp32 reconstruction, 16 elems/lane)
  float q[16];
  {
    const size_t base = (size_t)row * DQK + lane * 16;
    bf16x8 h0 = *(const bf16x8*)(qh + base);
    bf16x8 h1 = *(const bf16x8*)(qh + base + 8);
    bf16x8 l0 = *(const bf16x8*)(ql + base);
    bf16x8 l1 = *(const bf16x8*)(ql + base + 8);
#pragma unroll
    for (int t = 0; t < 8; ++t) {
      q[t] = (float)h0[t] + (float)l0[t];
      q[8 + t] = (float)h1[t] + (float)l1[t];
    }
  }

  // pass B: candidates within BAND of approx max -> exact recompute
  const float T = m0 - 1024.0f;  // band: 640 needed + ~200 error + margin
  float m = -3.0e38f;            // corrected max == TRUE row max
  for (int base = 0; base < len; base += 64) {
    const int j = base + lane;
    const bool cand = (j < len) && (rbw[j] >= T);
    unsigned long long mask = __ballot(cand);
    while (mask) {
      const int jj = base + (int)__builtin_ctzll(mask);
      mask &= mask - 1;
      const size_t kb = (size_t)jj * DQK + lane * 16;
      bf16x8 h0 = *(const bf16x8*)(kh + kb);
      bf16x8 h1 = *(const bf16x8*)(kh + kb + 8);
      bf16x8 l0 = *(const bf16x8*)(kl + kb);
      bf16x8 l1 = *(const bf16x8*)(kl + kb + 8);
      float d = 0.f;
#pragma unroll
      for (int t = 0; t < 8; ++t) {
        d += q[t] * ((float)h0[t] + (float)l0[t]);
        d += q[8 + t] * ((float)h1[t] + (float)l1[t]);
      }
#pragma unroll
      for (int o = 32; o > 0; o >>= 1) d += __shfl_xor(d, o);
      if (lane == 0) rbw[jj] = d;
      m = fmaxf(m, d);
    }
  }
  __syncthreads();

  // pass C: e = exp((s-m)/32) into LDS, sum
  float lsum = 0.f;
  for (int j = lane * 4; j < len; j += 256) {
    float4 v = *(float4*)&rbw[j];
    float4 e;
    e.x = (j + 0 < len) ? __expf((v.x - m) * 0.03125f) : 0.f;
    e.y = (j + 1 < len) ? __expf((v.y - m) * 0.03125f) : 0.f;
    e.z = (j + 2 < len) ? __expf((v.z - m) * 0.03125f) : 0.f;
    e.w = (j + 3 < len) ? __expf((v.w - m) * 0.03125f) : 0.f;
    *(float4*)&rbw[j] = e;
    lsum += e.x + e.y + e.z + e.w;
  }
#pragma unroll
  for (int o = 32; o > 0; o >>= 1) lsum += __shfl_xor(lsum, o);
  const float inv = 1.0f / lsum;
  __syncthreads();

  // pass D: write P bf16 in place (row-owned slot), zero-fill to ext
  bf16* prow = (bf16*)srow;
  for (int j = lane * 8; j < ext; j += 512) {
    bf16x8 o8;
#pragma unroll
    for (int t = 0; t < 8; ++t) {
      const int jj = j + t;
      const float v = (jj < len) ? rbw[jj] * inv : 0.f;
      o8[t] = (bf16)v;
    }
    *(bf16x8*)(prow + j) = o8;
  }
}

// ---------------- K4: O = P V, balanced split-K over causal extent ----------
// P lives in-place in S: ld = 8192 elements. Partials fp32 tight-packed:
// slice1 rows>=1024 @0, slice2 rows>=2048 @3M floats, slice3 rows>=3072 @5M.
__global__ __launch_bounds__(256, 2) void pv_kernel(const bf16* __restrict__ P,
                                                    const bf16* __restrict__ vt,
                                                    float* __restrict__ out,
                                                    float* __restrict__ part) {
  __shared__ bf16 sA[128 * 32];
  __shared__ bf16 sB[128 * 32];
  const int g = blockIdx.x >> 3;
  const int bn = blockIdx.x & 7;
  int bm, slice;
  if (g < 8) {
    bm = g;
    slice = 0;
  } else if (g < 24) {
    const int i = g - 8;
    bm = 8 + (i >> 1);
    slice = i & 1;
  } else if (g < 48) {
    const int i = g - 24;
    bm = 16 + i / 3;
    slice = i % 3;
  } else {
    const int i = g - 48;
    bm = 24 + (i >> 2);
    slice = i & 3;
  }
  const int ks0 = slice * 32;
  const int kend = (bm + 1) * 4;
  const int nk = (ks0 + 32 < kend) ? ks0 + 32 : kend;

  const int wid = threadIdx.x >> 6;
  const int lane = threadIdx.x & 63;
  const int wr = (wid >> 1) * 64;
  const int wc = (wid & 1) * 64;

  f32x4 acc[4][4];
#pragma unroll
  for (int i = 0; i < 4; ++i)
#pragma unroll
    for (int j = 0; j < 4; ++j) acc[i][j] = (f32x4)(0.0f);

  for (int kt = ks0; kt < nk; ++kt) {
    const int k0 = kt * 32;
    __syncthreads();
    stage_tile(P, 2 * SEQ, bm * 128, k0, sA, wid, lane);  // ld = 8192
    stage_tile(vt, SEQ, bn * 128, k0, sB, wid, lane);
    __syncthreads();
    bf16x8 a[4], b[4];
#pragma unroll
    for (int i = 0; i < 4; ++i) a[i] = ldsfrag(sA, wr + i * 16, lane);
#pragma unroll
    for (int j = 0; j < 4; ++j) b[j] = ldsfrag(sB, wc + j * 16, lane);
#pragma unroll
    for (int i = 0; i < 4; ++i)
#pragma unroll
      for (int j = 0; j < 4; ++j)
        acc[i][j] = __builtin_amdgcn_mfma_f32_16x16x32_bf16(a[i], b[j],
                                                            acc[i][j], 0, 0, 0);
  }

  float* dst;
  int rbase;
  if (slice == 0) {
    dst = out;
    rbase = 0;
  } else if (slice == 1) {
    dst = part;
    rbase = 1024;
  } else if (slice == 2) {
    dst = part + 3145728;
    rbase = 2048;
  } else {
    dst = part + 5242880;
    rbase = 3072;
  }
  const int r0 = bm * 128 + wr + ((lane >> 4) * 4);
  const int c0 = bn * 128 + wc + (lane & 15);
#pragma unroll
  for (int i = 0; i < 4; ++i)
#pragma unroll
    for (int j = 0; j < 4; ++j)
#pragma unroll
      for (int r = 0; r < 4; ++r)
        dst[(size_t)(r0 + i * 16 + r - rbase) * DV + (c0 + j * 16)] =
            acc[i][j][r];
}

// ---------------- K5: add split-K partial slices into out -------------------
__global__ __launch_bounds__(256) void pv_reduce(const float* __restrict__ part,
                                                 float* __restrict__ out) {
  const int idx = blockIdx.x * 256 + threadIdx.x;  // (4096-1024)*1024/4
  const int r = 1024 + (idx >> 8);
  const int c4 = (idx & 255) * 4;
  const size_t o = (size_t)r * DV + c4;
  float4 acc = *(float4*)&out[o];
  const float4 p1 = *(const float4*)&part[(size_t)(r - 1024) * DV + c4];
  acc.x += p1.x; acc.y += p1.y; acc.z += p1.z; acc.w += p1.w;
  if (r >= 2048) {
    const float4 p2 =
        *(const float4*)&part[3145728 + (size_t)(r - 2048) * DV + c4];
    acc.x += p2.x; acc.y += p2.y; acc.z += p2.z; acc.w += p2.w;
  }
  if (r >= 3072) {
    const float4 p3 =
        *(const float4*)&part[5242880 + (size_t)(r - 3072) * DV + c4];
    acc.x += p3.x; acc.y += p3.y; acc.z += p3.z; acc.w += p3.w;
  }
  *(float4*)&out[o] = acc;
}

// ---------------- launch ----------------
extern "C" void kernel_launch(void* const* d_in, const int* in_sizes, int n_in,
                              void* d_out, int out_size, void* d_ws,
                              size_t ws_size, hipStream_t stream) {
  const float* x = (const float*)d_in[0];
  const float* Wq = (const float*)d_in[1];
  const float* Wk = (const float*)d_in[2];
  const float* Wv = (const float*)d_in[3];
  float* out = (float*)d_out;
  char* ws = (char*)d_ws;

  const size_t MB = 1024 * 1024;
  // Lifetimes: qh/ql/kh/kl live proj->softmax; vt live proj->PV;
  // S@40..104 live score->PV (P written in-place by softmax);
  // xh/xl/w* (inside 40..104) dead before score writes S;
  // part@0..24 (over dead qh/ql/kh) written by PV, read by reduce.
  const size_t OFF_QH = 0, OFF_QL = 8 * MB, OFF_KH = 16 * MB, OFF_KL = 24 * MB;
  const size_t OFF_PART = 0;  // 24 MB fp32 tight-packed
  const size_t OFF_VT = 32 * MB;
  const size_t OFF_S = 40 * MB;
  const size_t OFF_XH = 40 * MB, OFF_XL = 48 * MB;
  const size_t OFF_WQH = 56 * MB, OFF_WQL = 58 * MB;
  const size_t OFF_WKH = 60 * MB, OFF_WKL = 62 * MB, OFF_WVT = 64 * MB;
  const size_t NEEDED = 104 * MB;
  if (ws_size < NEEDED) return;

  bf16* qh = (bf16*)(ws + OFF_QH);
  bf16* ql = (bf16*)(ws + OFF_QL);
  bf16* kh = (bf16*)(ws + OFF_KH);
  bf16* kl = (bf16*)(ws + OFF_KL);
  float* part = (float*)(ws + OFF_PART);
  bf16* vt = (bf16*)(ws + OFF_VT);
  float* S = (float*)(ws + OFF_S);
  bf16* xh = (bf16*)(ws + OFF_XH);
  bf16* xl = (bf16*)(ws + OFF_XL);
  bf16* wqh = (bf16*)(ws + OFF_WQH);
  bf16* wql = (bf16*)(ws + OFF_WQL);
  bf16* wkh = (bf16*)(ws + OFF_WKH);
  bf16* wkl = (bf16*)(ws + OFF_WKL);
  bf16* wvt = (bf16*)(ws + OFF_WVT);

  // K0: conversions
  split_f32<<<(SEQ * DIN / 4 + 255) / 256, 256, 0, stream>>>(x, xh, xl,
                                                             SEQ * DIN / 4);
  wtrans<true><<<1024, 256, 0, stream>>>(Wq, wqh, wql);
  wtrans<true><<<1024, 256, 0, stream>>>(Wk, wkh, wkl);
  wtrans<false><<<1024, 256, 0, stream>>>(Wv, wvt, nullptr);

  // K1: fused projections (Q split, K split, V^T plain) — 768 blocks
  fused_proj<<<768, 256, 0, stream>>>(xh, xl, wqh, wql, wkh, wkl, wvt, qh, ql,
                                      kh, kl, vt);

  // K2: causal scores, single bf16 pass -> S fp32
  score1<<<(SEQ / 128) * (SEQ / 128 + 1) / 2, 256, 0, stream>>>(qh, kh, S);

  // K3: softmax with exact near-max fixup; writes P bf16 in-place into S
  softmax_fixup<<<SEQ / 4, 256, 0, stream>>>(S, qh, ql, kh, kl);

  // K4: O = P V, balanced split-K (640 blocks)
  pv_kernel<<<640, 256, 0, stream>>>((const bf16*)S, vt, out, part);

  // K5: fold partial slices into out (rows >= 1024)
  pv_reduce<<<(SEQ - 1024) * DV / 4 / 256, 256, 0, stream>>>(part, out);
}